// Round 8
// baseline (78.490 us; speedup 1.0000x reference)
//
#include <hip/hip_runtime.h>

#define NUM_CLASSES 80
#define A_NUM 120000
#define B_NUM 8
#define N_BOX 64

typedef float f4 __attribute__((ext_vector_type(4)));

// R8: R2's compute-first structure + per-thread 2-anchor software pipeline.
// Each wave covers 128 anchors (two 64-chunks A,B):
//   stage boxes -> barrier (before ANY stores: its vmcnt drain covers only
//   cheap loads) -> IoU-A -> A's 22 nt stores -> IoU-B (A's stores drain
//   under B's ~3.3Kcy VALU: per-wave guaranteed overlap) -> B's stores.
// Store supply is continuous through the kernel body instead of wave-tail
// bursts; wave count halves (better div-chain ILP). Numerics identical
// to R2 (IEEE div, contract off, first-max argmax).

__device__ __forceinline__ void process_chunk(
    const float4 anc, int a, int chunk0, int b, int wv, int lane, int tid,
    const float4* __restrict__ sbox, const float* __restrict__ sarea,
    const int* __restrict__ slab, int* __restrict__ scls,
    float* __restrict__ out)
{
#pragma clang fp contract(off)
    const float wa = anc.z - anc.x;
    const float ha = anc.w - anc.y;
    const float area_a = wa * ha;

    float best_iou = -1.0f;
    int   best_j   = 0;
#pragma unroll 8
    for (int j = 0; j < N_BOX; ++j) {
        const float4 bx = sbox[j];                    // LDS broadcast
        const float ltx = fmaxf(anc.x, bx.x);
        const float lty = fmaxf(anc.y, bx.y);
        const float rbx = fminf(anc.z, bx.z);
        const float rby = fminf(anc.w, bx.w);
        const float w = fmaxf(rbx - ltx, 0.0f);
        const float h = fmaxf(rby - lty, 0.0f);
        const float inter = w * h;
        const float uni   = (area_a + sarea[j]) - inter;  // contract(off): no fma
        // union >= max(area) >= 1 (wh in [1,257]) so fmax(uni,1e-8) == uni.
        const float iou   = inter / uni;                  // IEEE div, matches np
        if (iou > best_iou) { best_iou = iou; best_j = j; }  // first-max wins
    }

    const bool positive = best_iou >= 0.5f;
    const bool ignore   = (best_iou > 0.4f) && !positive;
    const float state   = positive ? 1.0f : (ignore ? -1.0f : 0.0f);

    const float4 gt = sbox[best_j];
    f4 reg;
    reg.x = ((gt.x - anc.x) / wa) / 0.2f;
    reg.y = ((gt.y - anc.y) / ha) / 0.2f;
    reg.z = ((gt.z - anc.z) / wa) / 0.2f;
    reg.w = ((gt.w - anc.w) / ha) / 0.2f;

    const size_t CLS = (size_t)B_NUM * A_NUM * NUM_CLASSES;
    const size_t REG = (size_t)B_NUM * A_NUM * 4;
    f4* regout = (f4*)(out + CLS);
    __builtin_nontemporal_store(reg, &regout[(size_t)b * A_NUM + a]);
    __builtin_nontemporal_store(state, &out[CLS + REG + (size_t)b * A_NUM + a]);

    // Wave-local one-hot transpose. Same-wave LDS program order (write instr
    // completes before subsequent reads pass lgkmcnt) -> no barrier needed;
    // scls region is reused between chunk A and B safely for the same reason.
    scls[tid] = positive ? slab[best_j] : -1;
    f4* clsout = (f4*)out + ((size_t)b * A_NUM + chunk0) * 20;
#pragma unroll 8
    for (int i = 0; i < 20; ++i) {
        const int pos = i * 64 + lane;
        const int al  = pos / 20;          // local anchor within chunk [0,64)
        const int q   = pos - al * 20;     // which float4 within the 80-row
        const int lab = scls[wv * 64 + al];
        const int c0  = q * 4;
        f4 v;
        v.x = (lab == c0    ) ? 1.0f : 0.0f;
        v.y = (lab == c0 + 1) ? 1.0f : 0.0f;
        v.z = (lab == c0 + 2) ? 1.0f : 0.0f;
        v.w = (lab == c0 + 3) ? 1.0f : 0.0f;
        __builtin_nontemporal_store(v, &clsout[pos]);
    }
}

__global__ __launch_bounds__(256, 4) void compute_targets_kernel(
    const float* __restrict__ annotations,  // (B, 64, 5)
    const float4* __restrict__ anchors4,    // (A, 4)
    float* __restrict__ out)                // cls | reg | states, concat flat
{
#pragma clang fp contract(off)
    __shared__ float4 sbox[N_BOX];
    __shared__ float  sarea[N_BOX];
    __shared__ int    slab[N_BOX];
    __shared__ int    scls[256];

    const int tid  = threadIdx.x;
    const int wv   = tid >> 6;
    const int lane = tid & 63;
    const int b    = blockIdx.y;
    const int a0   = blockIdx.x * 512;         // block covers 512 anchors
    const int baseA = a0 + wv * 128;           // chunk A (64 anchors)
    const int baseB = baseA + 64;              // chunk B
    const bool validA = baseA < A_NUM;         // A_NUM % 64 == 0: all-or-none
    const bool validB = baseB < A_NUM;

    // Hoist both anchor loads: drained (cheaply) at the barrier, so phase B
    // starts with zero load latency.
    float4 ancA, ancB;
    if (validA) ancA = anchors4[baseA + lane];
    if (validB) ancB = anchors4[baseB + lane];

    if (tid < N_BOX) {
        const float* ann = annotations + ((size_t)b * N_BOX + tid) * 5;
        const float x0 = ann[0], y0 = ann[1], x1 = ann[2], y1 = ann[3];
        sbox[tid]  = make_float4(x0, y0, x1, y1);
        sarea[tid] = (x1 - x0) * (y1 - y0);   // same f32 ops as reference
        slab[tid]  = (int)ann[4];
    }
    __syncthreads();   // before any stores: drain covers loads only

    if (!validA) return;
    process_chunk(ancA, baseA + lane, baseA, b, wv, lane, tid,
                  sbox, sarea, slab, scls, out);
    if (!validB) return;
    process_chunk(ancB, baseB + lane, baseB, b, wv, lane, tid,
                  sbox, sarea, slab, scls, out);
}

extern "C" void kernel_launch(void* const* d_in, const int* in_sizes, int n_in,
                              void* d_out, int out_size, void* d_ws, size_t ws_size,
                              hipStream_t stream) {
    const float*  annotations = (const float*)d_in[0];   // (8, 64, 5)
    const float4* anchors     = (const float4*)d_in[1];  // (120000, 4)
    float* out = (float*)d_out;

    dim3 grid((A_NUM + 511) / 512, B_NUM);
    compute_targets_kernel<<<grid, 256, 0, stream>>>(annotations, anchors, out);
}

// Round 9
// 63.424 us; speedup vs baseline: 1.2375x; 1.2375x over previous
//
#include <hip/hip_runtime.h>

#define NUM_CLASSES 80
#define A_NUM 120000
#define B_NUM 8
#define N_BOX 64

typedef float f4 __attribute__((ext_vector_type(4)));

// R9 = R2 (best: 60.7us) with ONE change: the block-wide __syncthreads is
// deleted. Each wave stages the 64 boxes ITSELF into a per-wave LDS region
// (lane l loads box l): the RAW is wave-internal, ordered by the compiler's
// lgkmcnt waits — no s_barrier, no block-start convoy behind wave 0's
// annotation load. Everything else (IoU loop, nt stores, wave-local one-hot
// transpose) is byte-identical to R2. R7 validated this staging pattern.
__global__ __launch_bounds__(256, 4) void compute_targets_kernel(
    const float* __restrict__ annotations,  // (B, 64, 5)
    const float4* __restrict__ anchors4,    // (A, 4)
    float* __restrict__ out)                // cls | reg | states, concat flat
{
#pragma clang fp contract(off)
    __shared__ float4 sbox[4][N_BOX];
    __shared__ float  sarea[4][N_BOX];
    __shared__ int    slab[4][N_BOX];
    __shared__ int    scls[256];

    const int tid  = threadIdx.x;
    const int wv   = tid >> 6;
    const int lane = tid & 63;
    const int b    = blockIdx.y;
    const int a0   = blockIdx.x * 256;
    const int aw0  = a0 + wv * 64;   // wave's anchor base (A_NUM % 64 == 0)
    const int a    = a0 + tid;
    if (aw0 >= A_NUM) return;        // whole wave valid or whole wave out

    // Issue both vmem loads up front (anchor + this lane's box row).
    const float4 anc = anchors4[a];
    const float* ann = annotations + ((size_t)b * N_BOX + lane) * 5;
    const float x0 = ann[0], y0 = ann[1], x1 = ann[2], y1 = ann[3];
    const float lb = ann[4];

    // Per-wave LDS staging: no barrier anywhere in this kernel.
    sbox[wv][lane]  = make_float4(x0, y0, x1, y1);
    sarea[wv][lane] = (x1 - x0) * (y1 - y0);   // same f32 ops as reference
    slab[wv][lane]  = (int)lb;

    const float wa = anc.z - anc.x;
    const float ha = anc.w - anc.y;
    const float area_a = wa * ha;

    float best_iou = -1.0f;
    int   best_j   = 0;
#pragma unroll 8
    for (int j = 0; j < N_BOX; ++j) {
        const float4 bx = sbox[wv][j];                // LDS broadcast
        const float ltx = fmaxf(anc.x, bx.x);
        const float lty = fmaxf(anc.y, bx.y);
        const float rbx = fminf(anc.z, bx.z);
        const float rby = fminf(anc.w, bx.w);
        const float w = fmaxf(rbx - ltx, 0.0f);
        const float h = fmaxf(rby - lty, 0.0f);
        const float inter = w * h;
        const float uni   = (area_a + sarea[wv][j]) - inter;  // contract(off): no fma
        // union >= max(area) >= 1 (wh in [1,257]) so fmax(uni,1e-8) == uni.
        const float iou   = inter / uni;                      // IEEE div, matches np
        if (iou > best_iou) { best_iou = iou; best_j = j; }   // first-max wins
    }

    const bool positive = best_iou >= 0.5f;
    const bool ignore   = (best_iou > 0.4f) && !positive;
    const float state   = positive ? 1.0f : (ignore ? -1.0f : 0.0f);

    const float4 gt = sbox[wv][best_j];
    f4 reg;
    reg.x = ((gt.x - anc.x) / wa) / 0.2f;
    reg.y = ((gt.y - anc.y) / ha) / 0.2f;
    reg.z = ((gt.z - anc.z) / wa) / 0.2f;
    reg.w = ((gt.w - anc.w) / ha) / 0.2f;

    const size_t CLS = (size_t)B_NUM * A_NUM * NUM_CLASSES;
    const size_t REG = (size_t)B_NUM * A_NUM * 4;
    f4* regout = (f4*)(out + CLS);
    __builtin_nontemporal_store(reg, &regout[(size_t)b * A_NUM + a]);
    __builtin_nontemporal_store(state, &out[CLS + REG + (size_t)b * A_NUM + a]);

    // Wave-local one-hot transpose (same-wave LDS program order, no barrier).
    scls[tid] = positive ? slab[wv][best_j] : -1;
    f4* clsout = (f4*)out + ((size_t)b * A_NUM + aw0) * 20;
#pragma unroll
    for (int i = 0; i < 20; ++i) {
        const int pos = i * 64 + lane;
        const int al  = pos / 20;          // local anchor within wave [0,64)
        const int q   = pos - al * 20;     // which float4 within the 80-row
        const int lab = scls[wv * 64 + al];
        const int c0  = q * 4;
        f4 v;
        v.x = (lab == c0    ) ? 1.0f : 0.0f;
        v.y = (lab == c0 + 1) ? 1.0f : 0.0f;
        v.z = (lab == c0 + 2) ? 1.0f : 0.0f;
        v.w = (lab == c0 + 3) ? 1.0f : 0.0f;
        __builtin_nontemporal_store(v, &clsout[pos]);
    }
}

extern "C" void kernel_launch(void* const* d_in, const int* in_sizes, int n_in,
                              void* d_out, int out_size, void* d_ws, size_t ws_size,
                              hipStream_t stream) {
    const float*  annotations = (const float*)d_in[0];   // (8, 64, 5)
    const float4* anchors     = (const float4*)d_in[1];  // (120000, 4)
    float* out = (float*)d_out;

    dim3 grid((A_NUM + 255) / 256, B_NUM);
    compute_targets_kernel<<<grid, 256, 0, stream>>>(annotations, anchors, out);
}

// Round 10
// 60.979 us; speedup vs baseline: 1.2872x; 1.0401x over previous
//
#include <hip/hip_runtime.h>

#define NUM_CLASSES 80
#define A_NUM 120000
#define B_NUM 8
#define N_BOX 64

typedef float f4 __attribute__((ext_vector_type(4)));

// R10 = R2 restored verbatim (best measured: 60.7us; current file was the
// regressed R9). Ledger of falsified alternatives:
//   R3 occupancy 8 waves/SIMD: neutral. R4 plain stores: -9%.
//   R5/R6/R7 store-first (zero-fill then fixup): -25% — ANY wave issuing a
//     20-store burst before its compute convoys all resident waves on the
//     backed-up write queue (fence, barrier, or none — all equivalent).
//   R8 2-anchor software pipeline: -23%. R9 barrier-free staging: -4%.
// Conclusion: compute->store->die with 15K short waves IS the optimal
// supply schedule; hardware wave churn provides the overlap.
//
// One thread per (batch, anchor). Phase 1: first 64 threads stage GT boxes
// (+areas, labels) in LDS; one barrier (drains only cheap loads). Phase 2:
// per-anchor argmax-IoU over 64 boxes (IEEE div, contract off => bit-matches
// numpy; first-max argmax). Phase 3: nt reg/state stores, then WAVE-LOCAL
// LDS transpose (A_NUM % 64 == 0 -> no second barrier) and coalesced nt
// float4 one-hot stores.
__global__ __launch_bounds__(256, 4) void compute_targets_kernel(
    const float* __restrict__ annotations,  // (B, 64, 5)
    const float4* __restrict__ anchors4,    // (A, 4)
    float* __restrict__ out)                // cls | reg | states, concat flat
{
#pragma clang fp contract(off)
    __shared__ float4 sbox[N_BOX];
    __shared__ float  sarea[N_BOX];
    __shared__ int    slab[N_BOX];
    __shared__ int    scls[256];

    const int tid  = threadIdx.x;
    const int wv   = tid >> 6;
    const int lane = tid & 63;
    const int b    = blockIdx.y;
    const int a0   = blockIdx.x * 256;
    const int aw0  = a0 + wv * 64;   // wave's anchor base (A_NUM % 64 == 0)
    const int a    = a0 + tid;

    if (tid < N_BOX) {
        const float* ann = annotations + ((size_t)b * N_BOX + tid) * 5;
        const float x0 = ann[0], y0 = ann[1], x1 = ann[2], y1 = ann[3];
        sbox[tid]  = make_float4(x0, y0, x1, y1);
        sarea[tid] = (x1 - x0) * (y1 - y0);   // same f32 ops as reference
        slab[tid]  = (int)ann[4];
    }
    __syncthreads();

    if (aw0 >= A_NUM) return;        // whole wave valid or whole wave out

    const float4 anc = anchors4[a];
    const float wa = anc.z - anc.x;
    const float ha = anc.w - anc.y;
    const float area_a = wa * ha;

    float best_iou = -1.0f;
    int   best_j   = 0;
#pragma unroll 8
    for (int j = 0; j < N_BOX; ++j) {
        const float4 bx = sbox[j];                    // LDS broadcast
        const float ltx = fmaxf(anc.x, bx.x);
        const float lty = fmaxf(anc.y, bx.y);
        const float rbx = fminf(anc.z, bx.z);
        const float rby = fminf(anc.w, bx.w);
        const float w = fmaxf(rbx - ltx, 0.0f);
        const float h = fmaxf(rby - lty, 0.0f);
        const float inter = w * h;
        const float uni   = (area_a + sarea[j]) - inter;  // contract(off): no fma
        // union >= max(area) >= 1 (wh in [1,257]) so fmax(uni,1e-8) == uni.
        const float iou   = inter / uni;                  // IEEE div, matches np
        if (iou > best_iou) { best_iou = iou; best_j = j; }  // first-max wins
    }

    const bool positive = best_iou >= 0.5f;
    const bool ignore   = (best_iou > 0.4f) && !positive;
    const float state   = positive ? 1.0f : (ignore ? -1.0f : 0.0f);

    const float4 gt = sbox[best_j];
    f4 reg;
    reg.x = ((gt.x - anc.x) / wa) / 0.2f;
    reg.y = ((gt.y - anc.y) / ha) / 0.2f;
    reg.z = ((gt.z - anc.z) / wa) / 0.2f;
    reg.w = ((gt.w - anc.w) / ha) / 0.2f;

    const size_t CLS = (size_t)B_NUM * A_NUM * NUM_CLASSES;
    const size_t REG = (size_t)B_NUM * A_NUM * 4;
    f4* regout = (f4*)(out + CLS);
    __builtin_nontemporal_store(reg, &regout[(size_t)b * A_NUM + a]);
    __builtin_nontemporal_store(state, &out[CLS + REG + (size_t)b * A_NUM + a]);

    scls[tid] = positive ? slab[best_j] : -1;
    // No barrier: reads below touch only this wave's 64-slot segment.

    // cls_target: this wave's 64 anchors x 80 floats = 1280 float4, coalesced.
    f4* clsout = (f4*)out + ((size_t)b * A_NUM + aw0) * 20;
#pragma unroll
    for (int i = 0; i < 20; ++i) {
        const int pos = i * 64 + lane;
        const int al  = pos / 20;          // local anchor within wave [0,64)
        const int q   = pos - al * 20;     // which float4 within the 80-row
        const int lab = scls[wv * 64 + al];
        const int c0  = q * 4;
        f4 v;
        v.x = (lab == c0    ) ? 1.0f : 0.0f;
        v.y = (lab == c0 + 1) ? 1.0f : 0.0f;
        v.z = (lab == c0 + 2) ? 1.0f : 0.0f;
        v.w = (lab == c0 + 3) ? 1.0f : 0.0f;
        __builtin_nontemporal_store(v, &clsout[pos]);
    }
}

extern "C" void kernel_launch(void* const* d_in, const int* in_sizes, int n_in,
                              void* d_out, int out_size, void* d_ws, size_t ws_size,
                              hipStream_t stream) {
    const float*  annotations = (const float*)d_in[0];   // (8, 64, 5)
    const float4* anchors     = (const float4*)d_in[1];  // (120000, 4)
    float* out = (float*)d_out;

    dim3 grid((A_NUM + 255) / 256, B_NUM);
    compute_targets_kernel<<<grid, 256, 0, stream>>>(annotations, anchors, out);
}